// Round 1
// baseline (142.056 us; speedup 1.0000x reference)
//
#include <hip/hip_runtime.h>

constexpr int B    = 4;
constexpr int CIN  = 192;
constexpr int COUT = 192;
constexpr int NN   = 16384;
constexpr int KK   = 16;
constexpr int NG   = 4;    // groups
constexpr int GIN  = 48;   // fan_in per group
constexpr int GOUT = 48;   // out channels per group
constexpr int NT   = 64;   // nodes per block
constexpr int TPB  = 384;  // 6 waves/block; 4 blocks/CU -> 24 waves/CU (was 12)
constexpr int OST  = NT + 4;  // o_lds stride (68 floats = 272 B, 16B-aligned rows)

// ---------------------------------------------------------------------------
// Kernel 1: x (B, C, N) -> xt (B, G, N, 48): each (b,g) slice is a contiguous
// 3.15 MB region (fits one XCD's 4 MB L2); each node's group-slice is 192 B
// contiguous and 16B-aligned.  (unchanged — runs at ~L3 roofline)
// ---------------------------------------------------------------------------
__global__ __launch_bounds__(256) void transpose_x(const float* __restrict__ x,
                                                   float* __restrict__ xt) {
    __shared__ float tile[32][33];
    const int b  = blockIdx.z;
    const int n0 = blockIdx.x * 32;
    const int c0 = blockIdx.y * 32;
    const int tx = threadIdx.x;  // 0..31
    const int ty = threadIdx.y;  // 0..7
    const float* xb  = x  + (size_t)b * CIN * NN;
    float*       xtb = xt + (size_t)b * NN * CIN;   // = b * (NG*NN*GIN)
#pragma unroll
    for (int i = 0; i < 32; i += 8)
        tile[ty + i][tx] = xb[(size_t)(c0 + ty + i) * NN + (n0 + tx)];
    __syncthreads();
#pragma unroll
    for (int i = 0; i < 32; i += 8) {
        const int c = c0 + tx, n = n0 + ty + i;
        xtb[((size_t)(c / GIN) * NN + n) * GIN + (c % GIN)] = tile[tx][ty + i];
    }
}

// ---------------------------------------------------------------------------
// Kernel 2: block = (batch, 64-node tile); loops over the 4 channel groups.
//   b = blk & 3  ->  with %8 XCD round-robin, each XCD serves ONE batch.
//   1024 blocks, 4/CU, all co-resident -> XCD-wide group-phase sync:
//   gather working set per phase = 3.15 MB (~L2-resident).
//   TPB=384: 24 waves/CU for latency hiding of the random-L2 gather.
// ---------------------------------------------------------------------------
__global__ __launch_bounds__(TPB, 6) void gin_main(const float* __restrict__ xt,
                                                   const int*   __restrict__ idx,
                                                   const float* __restrict__ w,
                                                   const float* __restrict__ bias,
                                                   const float* __restrict__ eps,
                                                   float* __restrict__ out) {
    __shared__ __align__(16) float h_lds[NT * GIN];   // [64][48], linear
    __shared__ __align__(16) float o_lds[GOUT * OST]; // [48][68]
    __shared__ int   idx_lds[NT * KK];                // 4 KB

    const int tid = threadIdx.x;
    const int blk = blockIdx.x;
    const int b   = blk & 3;
    const int n0  = (blk >> 2) * NT;

    const float e1 = 1.0f + eps[0];

    // stage this tile's neighbor indices once (shared by all 4 groups)
    {
        const int* gi = idx + ((size_t)b * NN + n0) * KK;
        for (int i = tid; i < NT * KK; i += TPB) idx_lds[i] = gi[i];
    }

    // gather mapping: 12 lanes x float4 cover one 192 B node-slice
    const int e    = tid % 12;   // float4 index within slice
    const int isub = tid / 12;   // 0..31 (node sub-index)
    // gemm mapping
    const int co   = tid % GOUT; // 0..47
    const int q    = tid / GOUT; // 0..7 (node octant, 8 rows each)

    const float* xb = xt  + (size_t)b * NN * CIN;      // batch base
    float*       ob = out + (size_t)b * COUT * NN;

    __syncthreads();

    for (int g = 0; g < NG; ++g) {
        // prefetch this group's weight row + bias (consumed after the barrier,
        // loads stay in flight during the gather phase)
        float4 wv[12];
        {
            const float* wr = w + (size_t)(g * GOUT + co) * GIN;
#pragma unroll
            for (int ii = 0; ii < 12; ++ii) wv[ii] = ((const float4*)wr)[ii];
        }
        const float bi = bias[g * GOUT + co];

        // ---- Phase 1: gather + sum (float4 lanes) ----
        const float* xg = xb + (size_t)g * NN * GIN;   // (b,g) slice base
#pragma unroll
        for (int r = 0; r < 2; ++r) {
            const int i = isub + 32 * r;
            const float4 sv = ((const float4*)(xg + (size_t)(n0 + i) * GIN))[e];
            float4 acc;
            acc.x = e1 * sv.x; acc.y = e1 * sv.y;
            acc.z = e1 * sv.z; acc.w = e1 * sv.w;
            const int4* ip = (const int4*)(idx_lds + i * KK);
#pragma unroll
            for (int k4 = 0; k4 < 4; ++k4) {
                const int4 jj = ip[k4];
                const int js[4] = {jj.x, jj.y, jj.z, jj.w};
#pragma unroll
                for (int k = 0; k < 4; ++k) {
                    const float4 v = ((const float4*)(xg + (size_t)js[k] * GIN))[e];
                    acc.x += v.x; acc.y += v.y; acc.z += v.z; acc.w += v.w;
                }
            }
            ((float4*)(h_lds + i * GIN))[e] = acc;     // wave-linear, conflict-free
        }
        __syncthreads();

        // ---- Phase 2: grouped GEMM (weights in VGPRs, h broadcast from LDS) ----
        float a[8];
#pragma unroll
        for (int i2 = 0; i2 < 8; ++i2) {
            const int i = q * 8 + i2;
            const float* hr = h_lds + i * GIN;
            float s = bi;
#pragma unroll
            for (int ii = 0; ii < 12; ++ii) {
                const float4 hv = ((const float4*)hr)[ii];
                s = fmaf(wv[ii].x, hv.x, s);
                s = fmaf(wv[ii].y, hv.y, s);
                s = fmaf(wv[ii].z, hv.z, s);
                s = fmaf(wv[ii].w, hv.w, s);
            }
            a[i2] = fmaxf(s, 0.0f);
        }

        // ---- Phase 3: restage (float4, conflict-light) + coalesced write ----
        {
            float4* orow = (float4*)(o_lds + co * OST + q * 8);  // 272B rows, 16B ok
            orow[0] = make_float4(a[0], a[1], a[2], a[3]);
            orow[1] = make_float4(a[4], a[5], a[6], a[7]);
        }
        __syncthreads();

        const int row = tid / 16;   // 0..23
        const int ee  = tid % 16;   // float4 index within 64-float row
#pragma unroll
        for (int p = 0; p < 2; ++p) {
            const int r2 = p * 24 + row;
            const float4 v = ((const float4*)(o_lds + r2 * OST))[ee];
            ((float4*)(ob + (size_t)(g * GOUT + r2) * NN + n0))[ee] = v;
        }
        __syncthreads();   // o_lds/h_lds safe to overwrite next group
    }
}

// ---------------------------------------------------------------------------
extern "C" void kernel_launch(void* const* d_in, const int* in_sizes, int n_in,
                              void* d_out, int out_size, void* d_ws, size_t ws_size,
                              hipStream_t stream) {
    const float* x      = (const float*)d_in[0];
    const int*   edge   = (const int*)  d_in[1];  // edge_index[0] = first half
    const float* weight = (const float*)d_in[2];
    const float* bias   = (const float*)d_in[3];
    const float* eps    = (const float*)d_in[4];
    float*       out    = (float*)d_out;
    float*       xt     = (float*)d_ws;           // B*N*192 floats = 50.3 MB

    dim3 tblk(32, 8);
    dim3 tgrd(NN / 32, CIN / 32, B);
    transpose_x<<<tgrd, tblk, 0, stream>>>(x, xt);

    gin_main<<<B * (NN / NT), TPB, 0, stream>>>(xt, edge, weight, bias, eps, out);
}

// Round 2
// 100.650 us; speedup vs baseline: 1.4114x; 1.4114x over previous
//
#include <hip/hip_runtime.h>

constexpr int B    = 4;
constexpr int CIN  = 192;
constexpr int COUT = 192;
constexpr int NN   = 16384;
constexpr int KK   = 16;
constexpr int NG   = 4;    // groups
constexpr int GIN  = 48;   // fan_in per group
constexpr int GOUT = 48;   // out channels per group
constexpr int NT   = 32;   // nodes per block (was 64): 2048 blocks = 8/CU
constexpr int TPB  = 192;  // keep the proven 3-wave codegen
constexpr int OST  = NT + 4;  // o_lds stride (36 floats = 144 B, 16B-aligned rows)

// ---------------------------------------------------------------------------
// Kernel 1: x (B, C, N) -> xt (B, G, N, 48): each (b,g) slice is a contiguous
// 3.15 MB region (fits one XCD's 4 MB L2); each node's group-slice is 192 B
// contiguous and 16B-aligned.  (unchanged — runs at ~L3 roofline)
// ---------------------------------------------------------------------------
__global__ __launch_bounds__(256) void transpose_x(const float* __restrict__ x,
                                                   float* __restrict__ xt) {
    __shared__ float tile[32][33];
    const int b  = blockIdx.z;
    const int n0 = blockIdx.x * 32;
    const int c0 = blockIdx.y * 32;
    const int tx = threadIdx.x;  // 0..31
    const int ty = threadIdx.y;  // 0..7
    const float* xb  = x  + (size_t)b * CIN * NN;
    float*       xtb = xt + (size_t)b * NN * CIN;   // = b * (NG*NN*GIN)
#pragma unroll
    for (int i = 0; i < 32; i += 8)
        tile[ty + i][tx] = xb[(size_t)(c0 + ty + i) * NN + (n0 + tx)];
    __syncthreads();
#pragma unroll
    for (int i = 0; i < 32; i += 8) {
        const int c = c0 + tx, n = n0 + ty + i;
        xtb[((size_t)(c / GIN) * NN + n) * GIN + (c % GIN)] = tile[tx][ty + i];
    }
}

// ---------------------------------------------------------------------------
// Kernel 2: block = (batch, 32-node tile); loops over the 4 channel groups.
//   b = blk & 3  ->  with %8 XCD round-robin, each XCD serves ONE batch.
//   2048 blocks = 8/CU x 3 waves = 24 waves/CU (75% cap; was 12 waves/31.6%).
//   LDS/block ~15 KB -> all 8 blocks co-resident; XCD-wide group-phase sync:
//   gather working set per phase = 3.15 MB (~L2-resident).
//   NOTE: TPB stays 192 — Round-1 showed TPB=384 collapses codegen
//   (VGPR 64->40, weights spilled, FETCH 2.6x). Occupancy comes from more
//   blocks, not bigger blocks.
// ---------------------------------------------------------------------------
__global__ __launch_bounds__(TPB) void gin_main(const float* __restrict__ xt,
                                                const int*   __restrict__ idx,
                                                const float* __restrict__ w,
                                                const float* __restrict__ bias,
                                                const float* __restrict__ eps,
                                                float* __restrict__ out) {
    __shared__ __align__(16) float h_lds[NT * GIN];   // [32][48] = 6 KB
    __shared__ __align__(16) float o_lds[GOUT * OST]; // [48][36] = 6.75 KB
    __shared__ int   idx_lds[NT * KK];                // 2 KB

    const int tid = threadIdx.x;
    const int blk = blockIdx.x;
    const int b   = blk & 3;
    const int n0  = (blk >> 2) * NT;

    const float e1 = 1.0f + eps[0];

    // stage this tile's neighbor indices once (shared by all 4 groups)
    {
        const int* gi = idx + ((size_t)b * NN + n0) * KK;
        for (int i = tid; i < NT * KK; i += TPB) idx_lds[i] = gi[i];
    }

    // gather mapping: 12 lanes x float4 cover one 192 B node-slice
    const int e    = tid % 12;   // float4 index within slice
    const int isub = tid / 12;   // 0..15 (node sub-index)
    // gemm mapping
    const int co   = tid % GOUT; // 0..47
    const int q    = tid / GOUT; // 0..3 (node octant, 8 rows each)

    const float* xb = xt  + (size_t)b * NN * CIN;      // batch base
    float*       ob = out + (size_t)b * COUT * NN;

    __syncthreads();

    for (int g = 0; g < NG; ++g) {
        // prefetch this group's weight row + bias (consumed after the barrier,
        // loads stay in flight during the gather phase)
        float4 wv[12];
        {
            const float* wr = w + (size_t)(g * GOUT + co) * GIN;
#pragma unroll
            for (int ii = 0; ii < 12; ++ii) wv[ii] = ((const float4*)wr)[ii];
        }
        const float bi = bias[g * GOUT + co];

        // ---- Phase 1: gather + sum (float4 lanes) ----
        const float* xg = xb + (size_t)g * NN * GIN;   // (b,g) slice base
#pragma unroll
        for (int r = 0; r < 2; ++r) {
            const int i = isub + 16 * r;
            const float4 sv = ((const float4*)(xg + (size_t)(n0 + i) * GIN))[e];
            float4 acc;
            acc.x = e1 * sv.x; acc.y = e1 * sv.y;
            acc.z = e1 * sv.z; acc.w = e1 * sv.w;
            const int4* ip = (const int4*)(idx_lds + i * KK);
#pragma unroll
            for (int k4 = 0; k4 < 4; ++k4) {
                const int4 jj = ip[k4];
                const int js[4] = {jj.x, jj.y, jj.z, jj.w};
#pragma unroll
                for (int k = 0; k < 4; ++k) {
                    const float4 v = ((const float4*)(xg + (size_t)js[k] * GIN))[e];
                    acc.x += v.x; acc.y += v.y; acc.z += v.z; acc.w += v.w;
                }
            }
            ((float4*)(h_lds + i * GIN))[e] = acc;     // wave-linear, conflict-free
        }
        __syncthreads();

        // ---- Phase 2: grouped GEMM (weights in VGPRs, h broadcast from LDS) ----
        float a[8];
#pragma unroll
        for (int i2 = 0; i2 < 8; ++i2) {
            const int i = q * 8 + i2;
            const float* hr = h_lds + i * GIN;
            float s = bi;
#pragma unroll
            for (int ii = 0; ii < 12; ++ii) {
                const float4 hv = ((const float4*)hr)[ii];
                s = fmaf(wv[ii].x, hv.x, s);
                s = fmaf(wv[ii].y, hv.y, s);
                s = fmaf(wv[ii].z, hv.z, s);
                s = fmaf(wv[ii].w, hv.w, s);
            }
            a[i2] = fmaxf(s, 0.0f);
        }

        // ---- Phase 3: restage (float4, conflict-light) + coalesced write ----
        {
            float4* orow = (float4*)(o_lds + co * OST + q * 8);  // 144B rows, 16B ok
            orow[0] = make_float4(a[0], a[1], a[2], a[3]);
            orow[1] = make_float4(a[4], a[5], a[6], a[7]);
        }
        __syncthreads();

        // 48 rows x 32 floats = 384 float4; 192 threads x 2
        const int row = tid / 8;    // 0..23
        const int ee  = tid % 8;    // float4 index within 32-float row
#pragma unroll
        for (int p = 0; p < 2; ++p) {
            const int r2 = p * 24 + row;
            const float4 v = ((const float4*)(o_lds + r2 * OST))[ee];
            ((float4*)(ob + (size_t)(g * GOUT + r2) * NN + n0))[ee] = v;
        }
        __syncthreads();   // o_lds/h_lds safe to overwrite next group
    }
}

// ---------------------------------------------------------------------------
extern "C" void kernel_launch(void* const* d_in, const int* in_sizes, int n_in,
                              void* d_out, int out_size, void* d_ws, size_t ws_size,
                              hipStream_t stream) {
    const float* x      = (const float*)d_in[0];
    const int*   edge   = (const int*)  d_in[1];  // edge_index[0] = first half
    const float* weight = (const float*)d_in[2];
    const float* bias   = (const float*)d_in[3];
    const float* eps    = (const float*)d_in[4];
    float*       out    = (float*)d_out;
    float*       xt     = (float*)d_ws;           // B*N*192 floats = 50.3 MB

    dim3 tblk(32, 8);
    dim3 tgrd(NN / 32, CIN / 32, B);
    transpose_x<<<tgrd, tblk, 0, stream>>>(x, xt);

    gin_main<<<B * (NN / NT), TPB, 0, stream>>>(xt, edge, weight, bias, eps, out);
}